// Round 2
// baseline (1209.835 us; speedup 1.0000x reference)
//
#include <hip/hip_runtime.h>
#include <stdint.h>

// Problem constants
#define B_   128
#define T_   32
#define V_   32000
#define E_   128
#define H_   256
#define F_   2048
#define G4   1024   // 4*H
#define EF   2176   // E+F

typedef __attribute__((ext_vector_type(8))) short bh8;    // 8 x bf16 (raw bits)
typedef __attribute__((ext_vector_type(4))) short bh4;
typedef __attribute__((ext_vector_type(4))) float floatx4;

__device__ __forceinline__ short f2bf(float f) {
    union { float f; uint32_t u; } v; v.f = f;
    uint32_t r = (v.u + 0x7fffu + ((v.u >> 16) & 1u)) >> 16;   // RNE
    return (short)(uint16_t)r;
}

// ---------------------------------------------------------------------------
// Elementwise fp32 -> bf16 convert. n4 = count/4; grid*256 == n4 exactly.
// ---------------------------------------------------------------------------
__global__ __launch_bounds__(256) void cvt_f2b(
    const float* __restrict__ in, short* __restrict__ out)
{
    const size_t i = (size_t)blockIdx.x * 256 + threadIdx.x;
    const floatx4 v = *(const floatx4*)&in[i * 4];
    bh4 o;
    o[0] = f2bf(v[0]); o[1] = f2bf(v[1]); o[2] = f2bf(v[2]); o[3] = f2bf(v[3]);
    *(bh4*)&out[i * 4] = o;
}

// ---------------------------------------------------------------------------
// Transpose + convert: in fp32 (R x C) row-major -> out bf16 (C x R).
// R,C multiples of 64.
// ---------------------------------------------------------------------------
__global__ __launch_bounds__(256) void transpose_f2b(
    const float* __restrict__ in, short* __restrict__ out, int R, int C)
{
    __shared__ float tile[64][68];
    const int c0 = blockIdx.x * 64, r0 = blockIdx.y * 64;
    const int x = threadIdx.x & 15, y = threadIdx.x >> 4;
#pragma unroll
    for (int i = 0; i < 4; i++) {
        const int r = y + i * 16;
        *(floatx4*)&tile[r][x * 4] = *(const floatx4*)&in[(size_t)(r0 + r) * C + c0 + x * 4];
    }
    __syncthreads();
#pragma unroll
    for (int i = 0; i < 4; i++) {
        const int cc = y + i * 16;
        bh4 v;
        v[0] = f2bf(tile[x * 4 + 0][cc]);
        v[1] = f2bf(tile[x * 4 + 1][cc]);
        v[2] = f2bf(tile[x * 4 + 2][cc]);
        v[3] = f2bf(tile[x * 4 + 3][cc]);
        *(bh4*)&out[(size_t)(c0 + cc) * R + r0 + x * 4] = v;
    }
}

// ---------------------------------------------------------------------------
// Gather embedding rows + convert: out[(t*B + b)][e] = bf16(emb[captions[b][t]][e])
// ---------------------------------------------------------------------------
__global__ __launch_bounds__(256) void gather_embed(
    const int* __restrict__ captions, const float* __restrict__ emb,
    short* __restrict__ out)
{
    const int r = blockIdx.x * 16 + (threadIdx.x >> 4);   // r = t*B + b
    const int chunk = threadIdx.x & 15;                    // 8 floats each (E=128)
    const int t = r >> 7, b = r & 127;
    const int cap = captions[b * T_ + t];
    const floatx4* src = (const floatx4*)&emb[(size_t)cap * E_];
    const floatx4 a = src[chunk * 2], c = src[chunk * 2 + 1];
    bh8 o;
    o[0] = f2bf(a[0]); o[1] = f2bf(a[1]); o[2] = f2bf(a[2]); o[3] = f2bf(a[3]);
    o[4] = f2bf(c[0]); o[5] = f2bf(c[1]); o[6] = f2bf(c[2]); o[7] = f2bf(c[3]);
    ((bh8*)out)[(size_t)r * 16 + chunk] = o;
}

// ---------------------------------------------------------------------------
// NT GEMM: C(MxN) = A(MxK) @ B(NxK)^T, bf16 in, fp32 acc.
// 128x128 tile, BK=64, 4 waves 2x2, 4x4 x mfma_16x16x32_bf16 per wave.
// Out: fp32 (Cf) or bf16 (Cb). Optional fp32 biases added per column.
// M%128==0, N%128==0, K%64==0.
// ---------------------------------------------------------------------------
#define TM 128
#define TN 128
#define BKG 64

__global__ __launch_bounds__(256) void gemm_nt(
    const short* __restrict__ A, int lda,
    const short* __restrict__ B, int ldb,
    int K,
    float* __restrict__ Cf, short* __restrict__ Cb, int ldc,
    const float* __restrict__ bias1, const float* __restrict__ bias2)
{
    __shared__ short As[TM * BKG];
    __shared__ short Bs[TN * BKG];
    const int tid  = threadIdx.x;
    const int lane = tid & 63, quad = lane >> 4, l15 = lane & 15;
    const int wv   = tid >> 6;
    const int wr   = wv >> 1, wc = wv & 1;
    const short* Ab = A + (size_t)blockIdx.y * TM * lda;
    const short* Bb = B + (size_t)blockIdx.x * TN * ldb;
    const int srow = tid >> 3;
    const int skof = (tid & 7) << 3;

    floatx4 zero = {0.f, 0.f, 0.f, 0.f};
    floatx4 acc[4][4];
#pragma unroll
    for (int i = 0; i < 4; i++)
#pragma unroll
        for (int j = 0; j < 4; j++) acc[i][j] = zero;

    for (int k0 = 0; k0 < K; k0 += BKG) {
        __syncthreads();
#pragma unroll
        for (int j = 0; j < 4; j++) {
            const int r = j * 32 + srow;
            *(bh8*)&As[r * BKG + skof] = *(const bh8*)&Ab[(size_t)r * lda + k0 + skof];
            *(bh8*)&Bs[r * BKG + skof] = *(const bh8*)&Bb[(size_t)r * ldb + k0 + skof];
        }
        __syncthreads();
#pragma unroll
        for (int ks = 0; ks < 2; ks++) {
            bh8 af[4], bfr[4];
#pragma unroll
            for (int i = 0; i < 4; i++)
                af[i] = *(const bh8*)&As[(wr * 64 + i * 16 + l15) * BKG + ks * 32 + quad * 8];
#pragma unroll
            for (int j = 0; j < 4; j++)
                bfr[j] = *(const bh8*)&Bs[(wc * 64 + j * 16 + l15) * BKG + ks * 32 + quad * 8];
#pragma unroll
            for (int i = 0; i < 4; i++)
#pragma unroll
                for (int j = 0; j < 4; j++)
                    acc[i][j] = __builtin_amdgcn_mfma_f32_16x16x32_bf16(af[i], bfr[j], acc[i][j], 0, 0, 0);
        }
    }

    // C/D layout: col = lane&15, row = quad*4 + reg  [m89-verified]
#pragma unroll
    for (int i = 0; i < 4; i++) {
        const int m = blockIdx.y * TM + wr * 64 + i * 16 + quad * 4;
#pragma unroll
        for (int j = 0; j < 4; j++) {
            const int n = blockIdx.x * TN + wc * 64 + j * 16 + l15;
            float bias = 0.f;
            if (bias1) bias += bias1[n];
            if (bias2) bias += bias2[n];
#pragma unroll
            for (int r = 0; r < 4; r++) {
                const float v = acc[i][j][r] + bias;
                if (Cf) Cf[(size_t)(m + r) * ldc + n] = v;
                else    Cb[(size_t)(m + r) * ldc + n] = f2bf(v);
            }
        }
    }
}

// ---------------------------------------------------------------------------
// Persistent LSTM recurrence, 32 blocks x 256 threads (trivially co-resident).
// Block i owns hidden units [i*8, i*8+8) -> 32 gate columns.
// gates = h @ Whh_slice^T + e_t @ WihE_slice^T + fg (fg holds both biases).
// W slices pinned in LDS; c in registers; h double-buffered bf16 in global;
// device-scope sense-reversing barrier + all-thread fences between steps.
// ---------------------------------------------------------------------------
#define RBLK 32

__device__ __forceinline__ void gridbar(unsigned* bar) {
    __syncthreads();
    __threadfence();   // release: every thread drains/wb its h writes
    if (threadIdx.x == 0) {
        const unsigned g   = __hip_atomic_load(&bar[1], __ATOMIC_RELAXED, __HIP_MEMORY_SCOPE_AGENT);
        const unsigned old = __hip_atomic_fetch_add(&bar[0], 1u, __ATOMIC_ACQ_REL, __HIP_MEMORY_SCOPE_AGENT);
        if (old == RBLK - 1) {
            __hip_atomic_store(&bar[0], 0u, __ATOMIC_RELAXED, __HIP_MEMORY_SCOPE_AGENT);
            __hip_atomic_store(&bar[1], g + 1u, __ATOMIC_RELEASE, __HIP_MEMORY_SCOPE_AGENT);
        } else {
            while (__hip_atomic_load(&bar[1], __ATOMIC_ACQUIRE, __HIP_MEMORY_SCOPE_AGENT) == g)
                __builtin_amdgcn_s_sleep(1);
        }
    }
    __syncthreads();
    __threadfence();   // acquire: every thread invalidates before re-reading h
}

__global__ __launch_bounds__(256) void recurrence(
    const short* __restrict__ Whh,   // bf16 (1024 x 256)
    const short* __restrict__ Wih,   // bf16 (1024 x 2176); cols [0,E) used here
    const float* __restrict__ fg,    // feat gates + b_ih + b_hh (128 x 1024) fp32
    const short* __restrict__ embB,  // bf16 (T*B x 128), row = t*B + b
    short* h0buf,                    // h ping (128 x 256) bf16; holds h0 on entry
    short* h1buf,                    // h pong
    const float* __restrict__ c0,    // (128 x 256) fp32
    short* __restrict__ Hall,        // (B*T x 256) bf16, row = b*T + t
    unsigned* bar)
{
    __shared__ short Ws[32 * 256];   // W_hh slice [q][k]  (16 KB)
    __shared__ short We[32 * 128];   // W_ih[:, :E] slice  (8 KB)
    __shared__ float Gs[128 * 32];   // gates tile [b][q]  (16 KB)
    const int tid  = threadIdx.x;
    const int lane = tid & 63, quad = lane >> 4, l15 = lane & 15, wv = tid >> 6;
    const int u0   = blockIdx.x * 8;

    // Stage weight slices: q in [0,32) -> gate col = (q>>3)*H + u0 + (q&7)
    {
        const int q = tid >> 3;
        const int col = (q >> 3) * H_ + u0 + (q & 7);
        {   // Whh: 32 shorts per thread
            const int ko = (tid & 7) * 32;
            const bh8* src = (const bh8*)&Whh[(size_t)col * H_ + ko];
            bh8* dst = (bh8*)&Ws[q * 256 + ko];
#pragma unroll
            for (int i = 0; i < 4; i++) dst[i] = src[i];
        }
        {   // WihE: 16 shorts per thread
            const int ko = (tid & 7) * 16;
            const bh8* src = (const bh8*)&Wih[(size_t)col * EF + ko];
            bh8* dst = (bh8*)&We[q * 128 + ko];
            dst[0] = src[0]; dst[1] = src[1];
        }
    }

    const int uu = tid & 7, bb = tid >> 3;   // thread owns (b=bb+32k, u=u0+uu)
    float c[4];
#pragma unroll
    for (int k = 0; k < 4; k++) c[k] = c0[(bb + 32 * k) * H_ + u0 + uu];
    __syncthreads();

    for (int t = 0; t < T_; t++) {
        const short* hr = (t & 1) ? h1buf : h0buf;
        short*       hw = (t & 1) ? h0buf : h1buf;
        const short* et = embB + (size_t)t * B_ * E_;

        floatx4 zero = {0.f, 0.f, 0.f, 0.f};
        floatx4 acc[2][2];
#pragma unroll
        for (int i = 0; i < 2; i++)
#pragma unroll
            for (int j = 0; j < 2; j++) acc[i][j] = zero;

        // h @ Whh^T  (K=256)
#pragma unroll
        for (int s = 0; s < 8; s++) {
            bh8 af[2], bfr[2];
#pragma unroll
            for (int i = 0; i < 2; i++)
                af[i] = *(const bh8*)&hr[(wv * 32 + i * 16 + l15) * H_ + s * 32 + quad * 8];
#pragma unroll
            for (int j = 0; j < 2; j++)
                bfr[j] = *(const bh8*)&Ws[(j * 16 + l15) * 256 + s * 32 + quad * 8];
#pragma unroll
            for (int i = 0; i < 2; i++)
#pragma unroll
                for (int j = 0; j < 2; j++)
                    acc[i][j] = __builtin_amdgcn_mfma_f32_16x16x32_bf16(af[i], bfr[j], acc[i][j], 0, 0, 0);
        }
        // e_t @ WihE^T  (K=128)
#pragma unroll
        for (int s = 0; s < 4; s++) {
            bh8 af[2], bfr[2];
#pragma unroll
            for (int i = 0; i < 2; i++)
                af[i] = *(const bh8*)&et[(wv * 32 + i * 16 + l15) * E_ + s * 32 + quad * 8];
#pragma unroll
            for (int j = 0; j < 2; j++)
                bfr[j] = *(const bh8*)&We[(j * 16 + l15) * 128 + s * 32 + quad * 8];
#pragma unroll
            for (int i = 0; i < 2; i++)
#pragma unroll
                for (int j = 0; j < 2; j++)
                    acc[i][j] = __builtin_amdgcn_mfma_f32_16x16x32_bf16(af[i], bfr[j], acc[i][j], 0, 0, 0);
        }
#pragma unroll
        for (int i = 0; i < 2; i++)
#pragma unroll
            for (int j = 0; j < 2; j++)
#pragma unroll
                for (int r = 0; r < 4; r++)
                    Gs[(wv * 32 + i * 16 + quad * 4 + r) * 32 + j * 16 + l15] = acc[i][j][r];
        __syncthreads();

        // LSTM pointwise: 4 (b,u) pairs per thread, fp32 state
#pragma unroll
        for (int k = 0; k < 4; k++) {
            const int b     = bb + 32 * k;
            const int gbase = b * G4 + u0 + uu;
            const float xi = Gs[b * 32 + uu]      + fg[gbase];
            const float xf = Gs[b * 32 + 8 + uu]  + fg[gbase + 256];
            const float xg = Gs[b * 32 + 16 + uu] + fg[gbase + 512];
            const float xo = Gs[b * 32 + 24 + uu] + fg[gbase + 768];
            const float ig  = 1.f / (1.f + __expf(-xi));
            const float fgt = 1.f / (1.f + __expf(-xf));
            const float gg  = tanhf(xg);
            const float og  = 1.f / (1.f + __expf(-xo));
            c[k] = fgt * c[k] + ig * gg;
            const float h = og * tanhf(c[k]);
            const short hb = f2bf(h);
            hw[b * H_ + u0 + uu] = hb;
            Hall[(size_t)(b * T_ + t) * H_ + u0 + uu] = hb;
        }
        if (t < T_ - 1) gridbar(bar);
    }
}

// ---------------------------------------------------------------------------
// Host launcher
// ---------------------------------------------------------------------------
extern "C" void kernel_launch(void* const* d_in, const int* in_sizes, int n_in,
                              void* d_out, int out_size, void* d_ws, size_t ws_size,
                              hipStream_t stream)
{
    (void)in_sizes; (void)n_in; (void)out_size; (void)ws_size;
    const float* features   = (const float*)d_in[0];
    const int*   captions   = (const int*)  d_in[1];
    const float* embeddings = (const float*)d_in[2];
    const float* W_ih       = (const float*)d_in[3];
    const float* b_ih       = (const float*)d_in[4];
    const float* W_hh       = (const float*)d_in[5];
    const float* b_hh       = (const float*)d_in[6];
    const float* fc_W       = (const float*)d_in[7];
    const float* fc_b       = (const float*)d_in[8];
    // d_in[9..14] (Wa/Ua/va) are mathematically dead: softmax over a singleton
    // axis is identically 1, so context == features and mean_ann == features.
    const float* initH_W    = (const float*)d_in[15];
    const float* initH_b    = (const float*)d_in[16];
    const float* initC_W    = (const float*)d_in[17];
    const float* initC_b    = (const float*)d_in[18];
    float* out = (float*)d_out;

    char* ws = (char*)d_ws;
    size_t off = 0;
    auto alloc = [&](size_t bytes) -> void* {
        void* p = ws + off; off += (bytes + 255) & ~(size_t)255; return p;
    };
    unsigned* bar = (unsigned*)alloc(256);
    short* featB  = (short*)alloc((size_t)B_ * F_ * 2);        // features bf16
    short* WihB   = (short*)alloc((size_t)G4 * EF * 2);        // W_ih bf16 (same layout)
    short* WhhB   = (short*)alloc((size_t)G4 * H_ * 2);        // W_hh bf16
    short* fcWt   = (short*)alloc((size_t)V_ * H_ * 2);        // fc_W^T bf16 (V x H)
    short* iHt    = (short*)alloc((size_t)H_ * F_ * 2);        // initH_W^T bf16
    short* iCt    = (short*)alloc((size_t)H_ * F_ * 2);        // initC_W^T bf16
    short* embB   = (short*)alloc((size_t)B_ * T_ * E_ * 2);   // gathered embeds bf16
    float* fg     = (float*)alloc((size_t)B_ * G4 * 4);        // feat gates + biases fp32
    short* h0buf  = (short*)alloc((size_t)B_ * H_ * 2);
    short* h1buf  = (short*)alloc((size_t)B_ * H_ * 2);
    float* c0f    = (float*)alloc((size_t)B_ * H_ * 4);
    short* Hall   = (short*)alloc((size_t)B_ * T_ * H_ * 2);   // rows b*T+t
    // total ~27.9 MB

    hipMemsetAsync(bar, 0, 256, stream);

    cvt_f2b<<<dim3(B_ * F_ / 1024), 256, 0, stream>>>(features, featB);
    cvt_f2b<<<dim3(G4 * EF / 1024), 256, 0, stream>>>(W_ih, WihB);
    cvt_f2b<<<dim3(G4 * H_ / 1024), 256, 0, stream>>>(W_hh, WhhB);
    transpose_f2b<<<dim3(V_ / 64, H_ / 64), 256, 0, stream>>>(fc_W, fcWt, H_, V_);
    transpose_f2b<<<dim3(H_ / 64, F_ / 64), 256, 0, stream>>>(initH_W, iHt, F_, H_);
    transpose_f2b<<<dim3(H_ / 64, F_ / 64), 256, 0, stream>>>(initC_W, iCt, F_, H_);
    gather_embed<<<dim3(B_ * T_ / 16), 256, 0, stream>>>(captions, embeddings, embB);

    // h0 (bf16) and c0 (fp32): features @ init{H,C}_W + b
    gemm_nt<<<dim3(H_ / TN, 1), 256, 0, stream>>>(featB, F_, iHt, F_, F_,
                                                  nullptr, h0buf, H_, initH_b, nullptr);
    gemm_nt<<<dim3(H_ / TN, 1), 256, 0, stream>>>(featB, F_, iCt, F_, F_,
                                                  c0f, nullptr, H_, initC_b, nullptr);
    // feat_gates = features @ W_ih[:,E:]^T + b_ih + b_hh
    gemm_nt<<<dim3(G4 / TN, 1), 256, 0, stream>>>(featB, F_, WihB + E_, EF, F_,
                                                  fg, nullptr, G4, b_ih, b_hh);
    // 32-step LSTM recurrence (persistent; emb GEMM fused)
    recurrence<<<dim3(RBLK), 256, 0, stream>>>(WhhB, WihB, fg, embB,
                                               h0buf, h1buf, c0f, Hall, bar);
    // Deferred vocab projection: (B*T x H) @ fc_W -> out (B,T,V) fp32
    gemm_nt<<<dim3(V_ / TN, B_ * T_ / TM), 256, 0, stream>>>(Hall, H_, fcWt, H_, H_,
                                                             out, nullptr, V_, fc_b, nullptr);
}

// Round 3
// 998.077 us; speedup vs baseline: 1.2122x; 1.2122x over previous
//
#include <hip/hip_runtime.h>
#include <stdint.h>

// Problem constants
#define B_   128
#define T_   32
#define V_   32000
#define E_   128
#define H_   256
#define F_   2048
#define G4   1024   // 4*H
#define EF   2176   // E+F

typedef __attribute__((ext_vector_type(8))) short bh8;    // 8 x bf16 (raw bits)
typedef __attribute__((ext_vector_type(4))) short bh4;
typedef __attribute__((ext_vector_type(4))) float floatx4;

typedef __attribute__((address_space(1))) const void gv_t; // global
typedef __attribute__((address_space(3))) void lv_t;       // LDS

__device__ __forceinline__ short f2bf(float f) {
    union { float f; uint32_t u; } v; v.f = f;
    uint32_t r = (v.u + 0x7fffu + ((v.u >> 16) & 1u)) >> 16;   // RNE
    return (short)(uint16_t)r;
}

// ---------------------------------------------------------------------------
// Elementwise fp32 -> bf16 convert. grid*1024 elements exactly.
// ---------------------------------------------------------------------------
__global__ __launch_bounds__(256) void cvt_f2b(
    const float* __restrict__ in, short* __restrict__ out)
{
    const size_t i = (size_t)blockIdx.x * 256 + threadIdx.x;
    const floatx4 v = *(const floatx4*)&in[i * 4];
    bh4 o;
    o[0] = f2bf(v[0]); o[1] = f2bf(v[1]); o[2] = f2bf(v[2]); o[3] = f2bf(v[3]);
    *(bh4*)&out[i * 4] = o;
}

// ---------------------------------------------------------------------------
// Transpose + convert: in fp32 (R x C) row-major -> out bf16 (C x R).
// ---------------------------------------------------------------------------
__global__ __launch_bounds__(256) void transpose_f2b(
    const float* __restrict__ in, short* __restrict__ out, int R, int C)
{
    __shared__ float tile[64][68];
    const int c0 = blockIdx.x * 64, r0 = blockIdx.y * 64;
    const int x = threadIdx.x & 15, y = threadIdx.x >> 4;
#pragma unroll
    for (int i = 0; i < 4; i++) {
        const int r = y + i * 16;
        *(floatx4*)&tile[r][x * 4] = *(const floatx4*)&in[(size_t)(r0 + r) * C + c0 + x * 4];
    }
    __syncthreads();
#pragma unroll
    for (int i = 0; i < 4; i++) {
        const int cc = y + i * 16;
        bh4 v;
        v[0] = f2bf(tile[x * 4 + 0][cc]);
        v[1] = f2bf(tile[x * 4 + 1][cc]);
        v[2] = f2bf(tile[x * 4 + 2][cc]);
        v[3] = f2bf(tile[x * 4 + 3][cc]);
        *(bh4*)&out[(size_t)(c0 + cc) * R + r0 + x * 4] = v;
    }
}

// ---------------------------------------------------------------------------
// Gather embedding rows + convert: out[(t*B + b)][e] = bf16(emb[captions[b][t]][e])
// ---------------------------------------------------------------------------
__global__ __launch_bounds__(256) void gather_embed(
    const int* __restrict__ captions, const float* __restrict__ emb,
    short* __restrict__ out)
{
    const int r = blockIdx.x * 16 + (threadIdx.x >> 4);   // r = t*B + b
    const int chunk = threadIdx.x & 15;
    const int t = r >> 7, b = r & 127;
    const int cap = captions[b * T_ + t];
    const floatx4* src = (const floatx4*)&emb[(size_t)cap * E_];
    const floatx4 a = src[chunk * 2], c = src[chunk * 2 + 1];
    bh8 o;
    o[0] = f2bf(a[0]); o[1] = f2bf(a[1]); o[2] = f2bf(a[2]); o[3] = f2bf(a[3]);
    o[4] = f2bf(c[0]); o[5] = f2bf(c[1]); o[6] = f2bf(c[2]); o[7] = f2bf(c[3]);
    ((bh8*)out)[(size_t)r * 16 + chunk] = o;
}

// ---------------------------------------------------------------------------
// Shared NT GEMM tile body: C(128x128 tile) = A(MxK) @ B(NxK)^T.
// global_load_lds (16 B) staging, mfma_16x16x32_bf16, fp32 acc.
// ---------------------------------------------------------------------------
#define TM 128
#define TN 128
#define BKG 64

__device__ __forceinline__ void gemm_body(
    const short* __restrict__ A, int lda,
    const short* __restrict__ B, int ldb,
    int K,
    float* __restrict__ Cf, short* __restrict__ Cb, int ldc,
    const float* __restrict__ bias1, const float* __restrict__ bias2,
    int bx, int by, short* As, short* Bs)
{
    const int tid  = threadIdx.x;
    const int lane = tid & 63, quad = lane >> 4, l15 = lane & 15;
    const int wv   = tid >> 6;
    const int wr   = wv >> 1, wc = wv & 1;
    const short* Ab = A + (size_t)by * TM * lda;
    const short* Bb = B + (size_t)bx * TN * ldb;
    const int srow = tid >> 3;            // 32 rows per issue
    const int skof = (tid & 7) << 3;      // 8 shorts (16 B)

    floatx4 zero = {0.f, 0.f, 0.f, 0.f};
    floatx4 acc[4][4];
#pragma unroll
    for (int i = 0; i < 4; i++)
#pragma unroll
        for (int j = 0; j < 4; j++) acc[i][j] = zero;

    for (int k0 = 0; k0 < K; k0 += BKG) {
        __syncthreads();
#pragma unroll
        for (int j = 0; j < 4; j++) {
            const int r = j * 32 + srow;
            // LDS dest is wave-uniform base + lane*16 (matches [row][k] layout)
            __builtin_amdgcn_global_load_lds(
                (gv_t*)&Ab[(size_t)r * lda + k0 + skof],
                (lv_t*)&As[(j * 32 + wv * 8) * BKG], 16, 0, 0);
            __builtin_amdgcn_global_load_lds(
                (gv_t*)&Bb[(size_t)r * ldb + k0 + skof],
                (lv_t*)&Bs[(j * 32 + wv * 8) * BKG], 16, 0, 0);
        }
        __syncthreads();
#pragma unroll
        for (int ks = 0; ks < 2; ks++) {
            bh8 af[4], bfr[4];
#pragma unroll
            for (int i = 0; i < 4; i++)
                af[i] = *(const bh8*)&As[(wr * 64 + i * 16 + l15) * BKG + ks * 32 + quad * 8];
#pragma unroll
            for (int j = 0; j < 4; j++)
                bfr[j] = *(const bh8*)&Bs[(wc * 64 + j * 16 + l15) * BKG + ks * 32 + quad * 8];
#pragma unroll
            for (int i = 0; i < 4; i++)
#pragma unroll
                for (int j = 0; j < 4; j++)
                    acc[i][j] = __builtin_amdgcn_mfma_f32_16x16x32_bf16(af[i], bfr[j], acc[i][j], 0, 0, 0);
        }
    }

    // C/D layout: col = lane&15, row = quad*4 + reg  [m89-verified]
#pragma unroll
    for (int i = 0; i < 4; i++) {
        const int m = by * TM + wr * 64 + i * 16 + quad * 4;
#pragma unroll
        for (int j = 0; j < 4; j++) {
            const int n = bx * TN + wc * 64 + j * 16 + l15;
            float bias = 0.f;
            if (bias1) bias += bias1[n];
            if (bias2) bias += bias2[n];
#pragma unroll
            for (int r = 0; r < 4; r++) {
                const float v = acc[i][j][r] + bias;
                if (Cf) Cf[(size_t)(m + r) * ldc + n] = v;
                else    Cb[(size_t)(m + r) * ldc + n] = f2bf(v);
            }
        }
    }
}

__global__ __launch_bounds__(256) void gemm_nt(
    const short* __restrict__ A, int lda,
    const short* __restrict__ B, int ldb, int K,
    float* __restrict__ Cf, short* __restrict__ Cb, int ldc,
    const float* __restrict__ bias1, const float* __restrict__ bias2)
{
    __shared__ short As[TM * BKG];
    __shared__ short Bs[TN * BKG];
    gemm_body(A, lda, B, ldb, K, Cf, Cb, ldc, bias1, bias2,
              blockIdx.x, blockIdx.y, As, Bs);
}

// One launch for the three K=2048 init GEMMs (h0, c0, feat-gates). 12 blocks.
__global__ __launch_bounds__(256) void init_gemms(
    const short* __restrict__ featB, const short* __restrict__ iHt,
    const short* __restrict__ iCt, const short* __restrict__ WihB,
    short* __restrict__ h0, float* __restrict__ c0, float* __restrict__ fg,
    const float* __restrict__ initH_b, const float* __restrict__ initC_b,
    const float* __restrict__ b_ih, const float* __restrict__ b_hh)
{
    __shared__ short As[TM * BKG];
    __shared__ short Bs[TN * BKG];
    const int bid = blockIdx.x;
    if (bid < 2)
        gemm_body(featB, F_, iHt, F_, F_, nullptr, h0, H_, initH_b, nullptr, bid, 0, As, Bs);
    else if (bid < 4)
        gemm_body(featB, F_, iCt, F_, F_, c0, nullptr, H_, initC_b, nullptr, bid - 2, 0, As, Bs);
    else
        gemm_body(featB, F_, WihB + E_, EF, F_, fg, nullptr, G4, b_ih, b_hh, bid - 4, 0, As, Bs);
}

// ---------------------------------------------------------------------------
// Batch-partitioned LSTM recurrence — ZERO inter-block communication.
// 32 blocks x 256 threads; block owns batches [4*bx, 4*bx+4). Per step each
// block streams the full W_hh (512 KB, XCD-L2-hot) directly into MFMA
// B-fragments; h lives in LDS (M=16 mfma rows, 4 real); c in registers.
// ---------------------------------------------------------------------------
#define HS 272   // padded h row stride in shorts (+32 B -> 4-way LDS conflict max)

__global__ __launch_bounds__(256, 1) void recurrence2(
    const short* __restrict__ Whh,   // (1024 x 256) bf16
    const float* __restrict__ fg,    // (128 x 1024) fp32: feat gates + both biases
    const float* __restrict__ eg,    // (T*B x 1024) fp32: emb gates, row t*B+b
    const short* __restrict__ h0,    // (128 x 256) bf16
    const float* __restrict__ c0,    // (128 x 256) fp32
    short* __restrict__ Hall)        // (B*T x 256) bf16, row b*T+t
{
    __shared__ short hs[16 * HS];    // 8.5 KB  (rows 0-3 real, 4-15 pad)
    __shared__ float fgs[4 * G4];    // 16 KB
    __shared__ float Gs[4 * G4];     // 16 KB   gates_raw [b][col]
    const int tid  = threadIdx.x;
    const int lane = tid & 63, quad = lane >> 4, l15 = lane & 15, wv = tid >> 6;
    const int b0   = blockIdx.x * 4;
    const int u    = tid;            // pointwise: thread owns unit u, all 4 batches

    // Prologue: fg -> LDS, h0 -> LDS (zero the pad rows), c0 -> regs
#pragma unroll
    for (int i = 0; i < 16; i++) {
        const int idx = tid + i * 256;               // = b*1024 + col
        fgs[idx] = fg[(size_t)(b0 + (idx >> 10)) * G4 + (idx & 1023)];
    }
#pragma unroll
    for (int b = 0; b < 4; b++)
        hs[b * HS + tid] = h0[(size_t)(b0 + b) * H_ + tid];
#pragma unroll
    for (int rr = 4; rr < 16; rr++)
        hs[rr * HS + tid] = 0;
    float c[4];
#pragma unroll
    for (int b = 0; b < 4; b++) c[b] = c0[(size_t)(b0 + b) * H_ + u];
    __syncthreads();

    const floatx4 zero = {0.f, 0.f, 0.f, 0.f};
    for (int t = 0; t < T_; t++) {
        // Prefetch emb-gate terms early (independent of this step's MFMA)
        float egv[4][4];
#pragma unroll
        for (int b = 0; b < 4; b++)
#pragma unroll
            for (int g = 0; g < 4; g++)
                egv[b][g] = eg[(size_t)(t * B_ + b0 + b) * G4 + g * H_ + u];

        // A-fragments from LDS h (A[m=l15][k=quad*8+j])
        bh8 af[8];
#pragma unroll
        for (int s = 0; s < 8; s++)
            af[s] = *(const bh8*)&hs[l15 * HS + s * 32 + quad * 8];

        // Stream W_hh (B-side) straight from global (L2-hot), MFMA accumulate.
        // Wave wv covers gate cols [wv*256, wv*256+256).
        floatx4 acc[16];
#pragma unroll
        for (int j = 0; j < 16; j++) acc[j] = zero;
#pragma unroll
        for (int j = 0; j < 16; j++) {
            const short* wrow = &Whh[(size_t)(wv * 256 + j * 16 + l15) * H_ + quad * 8];
#pragma unroll
            for (int s = 0; s < 8; s++)
                acc[j] = __builtin_amdgcn_mfma_f32_16x16x32_bf16(
                    af[s], *(const bh8*)&wrow[s * 32], acc[j], 0, 0, 0);
        }

        // Batch rows 0-3 live in quad 0 (row = quad*4 + reg)
        if (quad == 0) {
#pragma unroll
            for (int j = 0; j < 16; j++) {
                const int col = wv * 256 + j * 16 + l15;
#pragma unroll
                for (int r = 0; r < 4; r++)
                    Gs[r * G4 + col] = acc[j][r];
            }
        }
        __syncthreads();

        // LSTM pointwise: unit u, batches 0-3, fp32 state
#pragma unroll
        for (int b = 0; b < 4; b++) {
            const float xi = Gs[b * G4 + u]          + fgs[b * G4 + u]          + egv[b][0];
            const float xf = Gs[b * G4 + H_ + u]     + fgs[b * G4 + H_ + u]     + egv[b][1];
            const float xg = Gs[b * G4 + 2 * H_ + u] + fgs[b * G4 + 2 * H_ + u] + egv[b][2];
            const float xo = Gs[b * G4 + 3 * H_ + u] + fgs[b * G4 + 3 * H_ + u] + egv[b][3];
            const float ig  = 1.f / (1.f + __expf(-xi));
            const float fgt = 1.f / (1.f + __expf(-xf));
            const float gg  = tanhf(xg);
            const float og  = 1.f / (1.f + __expf(-xo));
            c[b] = fgt * c[b] + ig * gg;
            const float h = og * tanhf(c[b]);
            const short hb = f2bf(h);
            hs[b * HS + u] = hb;
            Hall[(size_t)((b0 + b) * T_ + t) * H_ + u] = hb;
        }
        __syncthreads();
    }
}

// ---------------------------------------------------------------------------
// Host launcher
// ---------------------------------------------------------------------------
extern "C" void kernel_launch(void* const* d_in, const int* in_sizes, int n_in,
                              void* d_out, int out_size, void* d_ws, size_t ws_size,
                              hipStream_t stream)
{
    (void)in_sizes; (void)n_in; (void)out_size; (void)ws_size;
    const float* features   = (const float*)d_in[0];
    const int*   captions   = (const int*)  d_in[1];
    const float* embeddings = (const float*)d_in[2];
    const float* W_ih       = (const float*)d_in[3];
    const float* b_ih       = (const float*)d_in[4];
    const float* W_hh       = (const float*)d_in[5];
    const float* b_hh       = (const float*)d_in[6];
    const float* fc_W       = (const float*)d_in[7];
    const float* fc_b       = (const float*)d_in[8];
    // d_in[9..14] (Wa/Ua/va): softmax over singleton axis == 1 -> dead.
    const float* initH_W    = (const float*)d_in[15];
    const float* initH_b    = (const float*)d_in[16];
    const float* initC_W    = (const float*)d_in[17];
    const float* initC_b    = (const float*)d_in[18];
    float* out = (float*)d_out;

    char* ws = (char*)d_ws;
    size_t off = 0;
    auto alloc = [&](size_t bytes) -> void* {
        void* p = ws + off; off += (bytes + 255) & ~(size_t)255; return p;
    };
    // X region: eg (fp32, 16.78 MB) during recurrence, then fcWt (bf16, 16.38 MB)
    void*  X      = alloc((size_t)B_ * T_ * G4 * 4);
    float* eg     = (float*)X;
    short* fcWt   = (short*)X;
    short* featB  = (short*)alloc((size_t)B_ * F_ * 2);
    short* WihB   = (short*)alloc((size_t)G4 * EF * 2);
    short* WhhB   = (short*)alloc((size_t)G4 * H_ * 2);
    short* iHt    = (short*)alloc((size_t)H_ * F_ * 2);
    short* iCt    = (short*)alloc((size_t)H_ * F_ * 2);
    short* embB   = (short*)alloc((size_t)B_ * T_ * E_ * 2);
    float* fg     = (float*)alloc((size_t)B_ * G4 * 4);
    short* h0buf  = (short*)alloc((size_t)B_ * H_ * 2);
    float* c0f    = (float*)alloc((size_t)B_ * H_ * 4);
    short* Hall   = (short*)alloc((size_t)B_ * T_ * H_ * 2);
    // total ~28.2 MB

    cvt_f2b<<<dim3(B_ * F_ / 1024), 256, 0, stream>>>(features, featB);
    cvt_f2b<<<dim3(G4 * EF / 1024), 256, 0, stream>>>(W_ih, WihB);
    cvt_f2b<<<dim3(G4 * H_ / 1024), 256, 0, stream>>>(W_hh, WhhB);
    transpose_f2b<<<dim3(H_ / 64, F_ / 64), 256, 0, stream>>>(initH_W, iHt, F_, H_);
    transpose_f2b<<<dim3(H_ / 64, F_ / 64), 256, 0, stream>>>(initC_W, iCt, F_, H_);
    gather_embed<<<dim3(B_ * T_ / 16), 256, 0, stream>>>(captions, embeddings, embB);

    // h0 / c0 / feat-gates in one 12-block launch
    init_gemms<<<dim3(12), 256, 0, stream>>>(featB, iHt, iCt, WihB,
                                             h0buf, c0f, fg,
                                             initH_b, initC_b, b_ih, b_hh);
    // emb gates for all timesteps: (T*B x 128) @ W_ih[:,:E]^T -> (T*B x 1024)
    gemm_nt<<<dim3(G4 / TN, B_ * T_ / TM), 256, 0, stream>>>(embB, E_, WihB, EF, E_,
                                                             eg, nullptr, G4, nullptr, nullptr);
    // Zero-sync batch-partitioned recurrence
    recurrence2<<<dim3(32), 256, 0, stream>>>(WhhB, fg, eg, h0buf, c0f, Hall);

    // eg is dead now; build fc_W^T in the same region, then the big projection
    transpose_f2b<<<dim3(V_ / 64, H_ / 64), 256, 0, stream>>>(fc_W, fcWt, H_, V_);
    gemm_nt<<<dim3(V_ / TN, B_ * T_ / TM), 256, 0, stream>>>(Hall, H_, fcWt, H_, H_,
                                                             out, nullptr, V_, fc_b, nullptr);
}